// Round 7
// baseline (1114.049 us; speedup 1.0000x reference)
//
#include <hip/hip_runtime.h>
#include <hip/hip_bf16.h>

#define N_NODES  100000
#define N_EDGES  3200000
#define IN_FEATS 512
#define HIDDEN   256
#define N_CLASSES 64
#define NITER    10

#define SCAN_NB  49   // ceil(100000/2048)
#define NBKT     782  // ceil(100000/128) buckets of 128 nodes
#define NSUB     (NBKT * 8)
#define A1_GRID  2048
#define NCHUNK   (N_EDGES / 256)   // 12500

// d_out layout (floats): outputs[11][N][64] | p[N][10] | hl[N][10]
#define OUT_P_OFF  ((size_t)(NITER + 1) * N_NODES * N_CLASSES)
#define OUT_HL_OFF (OUT_P_OFF + (size_t)N_NODES * NITER)

// ws byte offsets
#define WS_META_INTS (4 * N_NODES + 128)
#define WS_CSR_OFF   ((size_t)WS_META_INTS * 4)
#define WS_W0F_OFF   (WS_CSR_OFF + (size_t)2 * N_EDGES * 4)
#define WS_W1F_OFF   (WS_W0F_OFF + 262144)
#define WS_SH0_OFF   (WS_W1F_OFF + 32768)
#define WS_SH1_OFF   (WS_SH0_OFF + (size_t)N_NODES * 64 * 2)
#define WS_BIN_OFF   (WS_SH1_OFF + (size_t)N_NODES * 64 * 2)
#define WS_NEED_W    (WS_SH0_OFF)
#define WS_NEED_BF   (WS_BIN_OFF)
#define WS_NEED_BIN  (WS_BIN_OFF + (size_t)N_EDGES * 8)

typedef _Float16 f16x8 __attribute__((ext_vector_type(8)));
typedef _Float16 f16x4 __attribute__((ext_vector_type(4)));
typedef float    f32x4 __attribute__((ext_vector_type(4)));

__device__ __forceinline__ float bflo(unsigned v) { return __uint_as_float(v << 16); }
__device__ __forceinline__ float bfhi(unsigned v) { return __uint_as_float(v & 0xffff0000u); }
__device__ __forceinline__ unsigned short f2bf(float f) {
    unsigned u = __float_as_uint(f);
    return (unsigned short)((u + 0x7fffu + ((u >> 16) & 1u)) >> 16);
}

// ---------------- dtype detection (int32 vs int64 edge_index) ----------------
__global__ void k_detect(const int* ei, int* flag) {
    if (threadIdx.x == 0 && blockIdx.x == 0) {
        int is64 = 1;
        for (int k = 0; k < 128; ++k) {
            if (ei[2 * k + 1] != 0) { is64 = 0; break; }
        }
        *flag = is64;
    }
}

__device__ __forceinline__ int edge_row(const void* ei, int is64, int e) {
    return is64 ? (int)((const long long*)ei)[e] : ((const int*)ei)[e];
}
__device__ __forceinline__ int edge_col(const void* ei, int is64, int e) {
    return is64 ? (int)((const long long*)ei)[(size_t)N_EDGES + e]
                : ((const int*)ei)[(size_t)N_EDGES + e];
}

// ---------------- degree count + (bucket,grp) histogram ----------------
__global__ __launch_bounds__(256) void k_count_hist(const void* ei, const int* flag,
        int* cnt, int* bhist) {
    __shared__ int lh[NSUB];
    for (int i = threadIdx.x; i < NSUB; i += 256) lh[i] = 0;
    __syncthreads();
    int is64 = *flag;
    for (int e = blockIdx.x * 256 + threadIdx.x; e < N_EDGES; e += 1024 * 256) {
        int c = edge_col(ei, is64, e);
        atomicAdd(&cnt[c], 1);
        atomicAdd(&lh[(c >> 7) * 8 + ((e >> 8) & 7)], 1);
    }
    __syncthreads();
    for (int i = threadIdx.x; i < NSUB; i += 256) {
        int v = lh[i];
        if (v) atomicAdd(&bhist[i], v);
    }
}

// ---------------- exclusive scan over cnt (N=100000) ----------------
__global__ __launch_bounds__(256) void k_scan1(const int* cnt, int* part) {
    __shared__ int sd[256];
    int b = blockIdx.x, t = threadIdx.x;
    int s = 0;
    for (int j = t; j < 2048; j += 256) {
        int idx = b * 2048 + j;
        if (idx < N_NODES) s += cnt[idx];
    }
    sd[t] = s;
    __syncthreads();
    for (int o = 128; o > 0; o >>= 1) {
        if (t < o) sd[t] += sd[t + o];
        __syncthreads();
    }
    if (t == 0) part[b] = sd[0];
}

__global__ __launch_bounds__(256) void k_scan2(int* part, int* offs) {
    __shared__ int sd[256];
    int t = threadIdx.x;
    sd[t] = (t < SCAN_NB) ? part[t] : 0;
    __syncthreads();
    for (int o = 1; o < 256; o <<= 1) {
        int add = (t >= o) ? sd[t - o] : 0;
        __syncthreads();
        sd[t] += add;
        __syncthreads();
    }
    if (t < SCAN_NB) part[t] = (t == 0) ? 0 : sd[t - 1];
    if (t == 0) offs[N_NODES] = N_EDGES;
}

__global__ __launch_bounds__(256) void k_scan3(const int* cnt, const int* part, int* offs) {
    __shared__ int sd[256];
    int b = blockIdx.x, t = threadIdx.x;
    int base = b * 2048 + t * 8;
    int local[8];
    int s = 0;
#pragma unroll
    for (int j = 0; j < 8; ++j) {
        int idx = base + j;
        int v = (idx < N_NODES) ? cnt[idx] : 0;
        local[j] = s;
        s += v;
    }
    sd[t] = s;
    __syncthreads();
    for (int o = 1; o < 256; o <<= 1) {
        int add = (t >= o) ? sd[t - o] : 0;
        __syncthreads();
        sd[t] += add;
        __syncthreads();
    }
    int tbase = part[b] + ((t == 0) ? 0 : sd[t - 1]);
#pragma unroll
    for (int j = 0; j < 8; ++j) {
        int idx = base + j;
        if (idx < N_NODES) offs[idx] = tbase + local[j];
    }
}

// ---------------- exclusive scan over bhist (NSUB=6256) ----------------
__global__ __launch_bounds__(256) void k_scan6k(const int* bhist, int* binoffs) {
    __shared__ int sd[256];
    int t = threadIdx.x;
    int base = t * 25;
    int loc[25];
    int s = 0;
#pragma unroll
    for (int j = 0; j < 25; ++j) {
        int idx = base + j;
        int v = (idx < NSUB) ? bhist[idx] : 0;
        loc[j] = s;
        s += v;
    }
    sd[t] = s;
    __syncthreads();
    for (int o = 1; o < 256; o <<= 1) {
        int add = (t >= o) ? sd[t - o] : 0;
        __syncthreads();
        sd[t] += add;
        __syncthreads();
    }
    int tb = (t == 0) ? 0 : sd[t - 1];
#pragma unroll
    for (int j = 0; j < 25; ++j) {
        int idx = base + j;
        if (idx < NSUB) binoffs[idx] = tb + loc[j];
    }
    if (t == 255) binoffs[NSUB] = N_EDGES;
}

__global__ void k_dinv(const int* cnt, float* dinv) {
    int i = blockIdx.x * 256 + threadIdx.x;
    if (i >= N_NODES) return;
    dinv[i] = rsqrtf((float)(cnt[i] + 1));
}

// ---------------- pass A1: bin edges by (bucket,grp), appended coalesced -----
__global__ __launch_bounds__(256) void k_bin(const void* ei, const int* flag,
        const int* __restrict__ binoffs, int* __restrict__ bincur,
        int2* __restrict__ bin) {
    int is64 = *flag;
    int B = blockIdx.x, g = B & 7;
    for (int ci = B; ci < NCHUNK; ci += A1_GRID) {
        int e = ci * 256 + threadIdx.x;
        int c = edge_col(ei, is64, e);
        int r = edge_row(ei, is64, e);
        int idx = (c >> 7) * 8 + g;
        int pos = binoffs[idx] + atomicAdd(&bincur[idx], 1);
        bin[pos] = make_int2(r, c);
    }
}

// ---------------- pass B: per-bucket scatter into L2-hot CSR slice -----------
__global__ __launch_bounds__(256) void k_fill_b(const int2* __restrict__ bin,
        const int* __restrict__ binoffs, const int* __restrict__ offs,
        const float* __restrict__ dinv, int2* __restrict__ csr) {
    __shared__ int lcur[128];
    int b = blockIdx.x;
    int lo = b << 7;
    if (threadIdx.x < 128) lcur[threadIdx.x] = 0;
    __syncthreads();
    int start = binoffs[b * 8], end = binoffs[(b + 1) * 8];
    for (int i = start + threadIdx.x; i < end; i += 256) {
        int2 rc = bin[i];
        int pos = offs[rc.y] + atomicAdd(&lcur[rc.y - lo], 1);
        csr[pos] = make_int2(rc.x, __float_as_int(dinv[rc.x] * dinv[rc.y]));
    }
}

// ---------------- fallback single-pass fill (ws too small for bin) -----------
#define FILL_GRID 3200
__global__ __launch_bounds__(256) void k_fill_part(const void* ei, const int* flag,
        const float* dinv, const int* offs, int* cursor, int2* csr) {
    const int g = blockIdx.x & 7;
    const int bi = blockIdx.x >> 3;
    const int lo = g * (N_NODES / 8);
    const int hi = lo + (N_NODES / 8);
    const int is64 = *flag;
    const int stride = (FILL_GRID >> 3) * 256;
    for (int e = bi * 256 + threadIdx.x; e < N_EDGES; e += stride) {
        int c = edge_col(ei, is64, e);
        if (c >= lo && c < hi) {
            int r = edge_row(ei, is64, e);
            int pos = offs[c] + atomicAdd(&cursor[c], 1);
            csr[pos] = make_int2(r, __float_as_int(dinv[r] * dinv[c]));
        }
    }
}

// -------- weight reshuffle to frag-ready fp16 (one dwordx4 per lane-frag) ----
__global__ void k_prep_w(const float* __restrict__ W0, const float* __restrict__ W1,
                         _Float16* __restrict__ W0f, _Float16* __restrict__ W1f) {
    int id = blockIdx.x * 256 + threadIdx.x;
    if (id < 16384) {
        int l = id & 63, c = (id >> 6) & 15, kkg = id >> 10;
        int n = c * 16 + (l & 15);
        int kb = kkg * 32 + ((l >> 4) * 8);
        f16x8 v;
#pragma unroll
        for (int j = 0; j < 8; ++j) v[j] = (_Float16)W0[(size_t)(kb + j) * HIDDEN + n];
        *(f16x8*)&W0f[(size_t)id * 8] = v;
    } else if (id < 16384 + 2048) {
        int id2 = id - 16384;
        int l = id2 & 63, c = (id2 >> 6) & 3, kkg = id2 >> 8;
        int n = c * 16 + (l & 15);
        int kb = kkg * 32 + ((l >> 4) * 8);
        f16x8 v;
#pragma unroll
        for (int j = 0; j < 8; ++j) v[j] = (_Float16)W1[(size_t)(kb + j) * N_CLASSES + n];
        *(f16x8*)&W1f[(size_t)id2 * 8] = v;
    }
}

// ---------------- MFMA fp16 fused encoder, v3: W through LDS ----------------
#define EBM 64
#define XS_STRIDE 72
#define H1_STRIDE 264
#define XS0   0
#define XS1   9216
#define WST0  18432
#define WST1  34816
#define W2ST0 34816
#define W2ST1 38912
__global__ __launch_bounds__(256) void k_encoder_mfma(
        const float* __restrict__ x, const _Float16* __restrict__ W0f,
        const float* __restrict__ b0, const _Float16* __restrict__ W1f,
        const float* __restrict__ b1, float* __restrict__ out,
        unsigned short* __restrict__ shadow, int write_shadow) {
    __shared__ char smem[51200];
    const int t = threadIdx.x;
    const int w = t >> 6, l = t & 63;
    const int g = l >> 4, r15 = l & 15;
    const int row0 = blockIdx.x * EBM;
    const int c4 = t & 15;
    const int srow0 = t >> 4;

    f32x4 acc[16];
#pragma unroll
    for (int c = 0; c < 16; ++c) acc[c] = (f32x4){0.f, 0.f, 0.f, 0.f};

    float4 xld[4];
    f16x8 wld[4];
#pragma unroll
    for (int q = 0; q < 4; ++q) {
        int grow = row0 + q * 16 + srow0;
        if (grow >= N_NODES) grow = N_NODES - 1;
        xld[q] = *(const float4*)&x[(size_t)grow * IN_FEATS + c4 * 4];
    }
#pragma unroll
    for (int q = 0; q < 4; ++q) wld[q] = *(const f16x8*)&W0f[(size_t)(q * 256 + t) * 8];
#pragma unroll
    for (int q = 0; q < 4; ++q) {
        f16x4 hv = {(_Float16)xld[q].x, (_Float16)xld[q].y, (_Float16)xld[q].z, (_Float16)xld[q].w};
        *(f16x4*)(smem + XS0 + ((q * 16 + srow0) * XS_STRIDE + c4 * 4) * 2) = hv;
    }
#pragma unroll
    for (int q = 0; q < 4; ++q)
        *(f16x8*)(smem + WST0 + (q * 256 + t) * 16) = wld[q];
    __syncthreads();

    for (int kkg = 0; kkg < 16; ++kkg) {
        const int kc = kkg >> 1, kk = kkg & 1;
        if (kkg < 15) {
#pragma unroll
            for (int q = 0; q < 4; ++q)
                wld[q] = *(const f16x8*)&W0f[(size_t)((kkg + 1) * 1024 + q * 256 + t) * 8];
        }
        if (kk == 0 && kc < 7) {
#pragma unroll
            for (int q = 0; q < 4; ++q) {
                int grow = row0 + q * 16 + srow0;
                if (grow >= N_NODES) grow = N_NODES - 1;
                xld[q] = *(const float4*)&x[(size_t)grow * IN_FEATS + (kc + 1) * 64 + c4 * 4];
            }
        }
        const char* xbase = smem + ((kc & 1) ? XS1 : XS0);
        const char* wbase = smem + ((kkg & 1) ? WST1 : WST0);
        f16x8 af = *(const f16x8*)(xbase + ((w * 16 + r15) * XS_STRIDE + kk * 32 + g * 8) * 2);
#pragma unroll
        for (int c = 0; c < 16; ++c) {
            f16x8 bf = *(const f16x8*)(wbase + ((c << 6) | l) * 16);
            acc[c] = __builtin_amdgcn_mfma_f32_16x16x32_f16(af, bf, acc[c], 0, 0, 0);
        }
        if (kkg < 15) {
            char* wdst = smem + ((kkg & 1) ? WST0 : WST1);
#pragma unroll
            for (int q = 0; q < 4; ++q)
                *(f16x8*)(wdst + (q * 256 + t) * 16) = wld[q];
        }
        if (kk == 1 && kc < 7) {
            char* xdst = smem + ((kc & 1) ? XS0 : XS1);
#pragma unroll
            for (int q = 0; q < 4; ++q) {
                f16x4 hv = {(_Float16)xld[q].x, (_Float16)xld[q].y, (_Float16)xld[q].z, (_Float16)xld[q].w};
                *(f16x4*)(xdst + ((q * 16 + srow0) * XS_STRIDE + c4 * 4) * 2) = hv;
            }
        }
        __syncthreads();
    }

    f16x8 w2ld = *(const f16x8*)&W1f[(size_t)t * 8];
#pragma unroll
    for (int c = 0; c < 16; ++c) {
        float bb = b0[c * 16 + r15];
#pragma unroll
        for (int i = 0; i < 4; ++i) {
            int row = w * 16 + g * 4 + i;
            *(_Float16*)(smem + (row * H1_STRIDE + c * 16 + r15) * 2) =
                (_Float16)fmaxf(acc[c][i] + bb, 0.f);
        }
    }
    *(f16x8*)(smem + W2ST0 + t * 16) = w2ld;
    __syncthreads();

    f32x4 acc2[4];
#pragma unroll
    for (int c = 0; c < 4; ++c) acc2[c] = (f32x4){0.f, 0.f, 0.f, 0.f};
    for (int kkg = 0; kkg < 8; ++kkg) {
        if (kkg < 7) w2ld = *(const f16x8*)&W1f[(size_t)((kkg + 1) * 256 + t) * 8];
        const char* wbase = smem + ((kkg & 1) ? W2ST1 : W2ST0);
        f16x8 af = *(const f16x8*)(smem + ((w * 16 + r15) * H1_STRIDE + kkg * 32 + g * 8) * 2);
#pragma unroll
        for (int c = 0; c < 4; ++c) {
            f16x8 bf = *(const f16x8*)(wbase + ((c << 6) | l) * 16);
            acc2[c] = __builtin_amdgcn_mfma_f32_16x16x32_f16(af, bf, acc2[c], 0, 0, 0);
        }
        if (kkg < 7)
            *(f16x8*)(smem + ((kkg & 1) ? W2ST0 : W2ST1) + t * 16) = w2ld;
        __syncthreads();
    }
#pragma unroll
    for (int c = 0; c < 4; ++c) {
        float bb = b1[c * 16 + r15];
#pragma unroll
        for (int i = 0; i < 4; ++i) {
            int row = row0 + w * 16 + g * 4 + i;
            if (row < N_NODES) {
                float v = acc2[c][i] + bb;
                int col = c * 16 + r15;
                out[(size_t)row * 64 + col] = v;
                if (write_shadow) shadow[(size_t)row * 64 + col] = f2bf(v);
            }
        }
    }
}

// ---------------- scalar fallback encoder ----------------
__global__ __launch_bounds__(256) void k_encoder(const float* __restrict__ x,
        const float* __restrict__ W0, const float* __restrict__ b0,
        const float* __restrict__ W1, const float* __restrict__ b1,
        float* __restrict__ out) {
    __shared__ float xsh[32][128];
    __shared__ float h1s[32][HIDDEN + 1];
    const int t = threadIdx.x;
    const int rg = t >> 6;
    const int cg = t & 63;
    const size_t row0 = (size_t)blockIdx.x * 32;
    float acc[8][4];
#pragma unroll
    for (int i = 0; i < 8; ++i)
        acc[i][0] = acc[i][1] = acc[i][2] = acc[i][3] = 0.f;
    for (int kc = 0; kc < 4; ++kc) {
        __syncthreads();
#pragma unroll
        for (int q = 0; q < 4; ++q) {
            int idx = t + q * 256;
            int r = idx >> 5, pos = idx & 31;
            *(float4*)&xsh[r][pos * 4] =
                *(const float4*)&x[(row0 + r) * IN_FEATS + kc * 128 + pos * 4];
        }
        __syncthreads();
        for (int kk = 0; kk < 128; kk += 4) {
            float4 xv[8];
#pragma unroll
            for (int i = 0; i < 8; ++i) xv[i] = *(const float4*)&xsh[rg * 8 + i][kk];
#pragma unroll
            for (int j = 0; j < 4; ++j) {
                float4 wv = *(const float4*)&W0[(size_t)(kc * 128 + kk + j) * HIDDEN + cg * 4];
#pragma unroll
                for (int i = 0; i < 8; ++i) {
                    float xj = (&xv[i].x)[j];
                    acc[i][0] = fmaf(xj, wv.x, acc[i][0]);
                    acc[i][1] = fmaf(xj, wv.y, acc[i][1]);
                    acc[i][2] = fmaf(xj, wv.z, acc[i][2]);
                    acc[i][3] = fmaf(xj, wv.w, acc[i][3]);
                }
            }
        }
    }
    float4 bb = *(const float4*)&b0[cg * 4];
#pragma unroll
    for (int i = 0; i < 8; ++i) {
        int r = rg * 8 + i;
        h1s[r][cg * 4 + 0] = fmaxf(acc[i][0] + bb.x, 0.f);
        h1s[r][cg * 4 + 1] = fmaxf(acc[i][1] + bb.y, 0.f);
        h1s[r][cg * 4 + 2] = fmaxf(acc[i][2] + bb.z, 0.f);
        h1s[r][cg * 4 + 3] = fmaxf(acc[i][3] + bb.w, 0.f);
    }
    __syncthreads();
    float a2[8];
#pragma unroll
    for (int i = 0; i < 8; ++i) a2[i] = 0.f;
    for (int k = 0; k < HIDDEN; ++k) {
        float wv = W1[(size_t)k * N_CLASSES + cg];
#pragma unroll
        for (int i = 0; i < 8; ++i) a2[i] = fmaf(h1s[rg * 8 + i][k], wv, a2[i]);
    }
    float bv = b1[cg];
#pragma unroll
    for (int i = 0; i < 8; ++i)
        out[(row0 + rg * 8 + i) * N_CLASSES + cg] = a2[i] + bv;
}

// ---------------- bf16-gather propagation: 2 nodes/wave, fp32 accumulate ------
__global__ __launch_bounds__(256) void k_prop_bf(
        const unsigned short* __restrict__ pin_bf, float* __restrict__ pout,
        unsigned short* __restrict__ pout_bf, const int* __restrict__ offs,
        const int2* __restrict__ csr, const float* __restrict__ dinv,
        const float* __restrict__ Wh, const float* __restrict__ bh,
        float* __restrict__ hl, int t) {
    int node = (blockIdx.x * 256 + threadIdx.x) >> 5;
    if (node >= N_NODES) return;
    int hlane = threadIdx.x & 31;
    int base = threadIdx.x & 32;
    float di = dinv[node];
    unsigned vs = *(const unsigned*)&pin_bf[(size_t)node * 64 + hlane * 2];
    float a0 = di * di * bflo(vs), a1 = di * di * bfhi(vs);
    float c0 = 0.f, c1 = 0.f;
    int e0 = offs[node], e1 = offs[node + 1];
    for (int eb = e0; eb < e1; eb += 32) {
        int n = e1 - eb; if (n > 32) n = 32;
        int idx = eb + hlane;
        int2 ew = csr[idx < e1 ? idx : e1 - 1];
        int j = 0;
        for (; j + 16 <= n; j += 16) {
            unsigned v[16]; float w[16];
#pragma unroll
            for (int q = 0; q < 16; ++q) {
                int s = __shfl(ew.x, base + j + q, 64);
                w[q] = __int_as_float(__shfl(ew.y, base + j + q, 64));
                v[q] = *(const unsigned*)&pin_bf[(size_t)s * 64 + hlane * 2];
            }
#pragma unroll
            for (int q = 0; q < 16; ++q) {
                if (q & 1) { c0 = fmaf(w[q], bflo(v[q]), c0); c1 = fmaf(w[q], bfhi(v[q]), c1); }
                else       { a0 = fmaf(w[q], bflo(v[q]), a0); a1 = fmaf(w[q], bfhi(v[q]), a1); }
            }
        }
        for (; j + 8 <= n; j += 8) {
            unsigned v[8]; float w[8];
#pragma unroll
            for (int q = 0; q < 8; ++q) {
                int s = __shfl(ew.x, base + j + q, 64);
                w[q] = __int_as_float(__shfl(ew.y, base + j + q, 64));
                v[q] = *(const unsigned*)&pin_bf[(size_t)s * 64 + hlane * 2];
            }
#pragma unroll
            for (int q = 0; q < 8; ++q) {
                if (q & 1) { c0 = fmaf(w[q], bflo(v[q]), c0); c1 = fmaf(w[q], bfhi(v[q]), c1); }
                else       { a0 = fmaf(w[q], bflo(v[q]), a0); a1 = fmaf(w[q], bfhi(v[q]), a1); }
            }
        }
        for (; j < n; ++j) {
            int s = __shfl(ew.x, base + j, 64);
            float w = __int_as_float(__shfl(ew.y, base + j, 64));
            unsigned v = *(const unsigned*)&pin_bf[(size_t)s * 64 + hlane * 2];
            a0 = fmaf(w, bflo(v), a0);
            a1 = fmaf(w, bfhi(v), a1);
        }
    }
    float fa = a0 + c0, fb = a1 + c1;
    *(float2*)&pout[(size_t)node * 64 + hlane * 2] = make_float2(fa, fb);
    *(unsigned*)&pout_bf[(size_t)node * 64 + hlane * 2] =
        (unsigned)f2bf(fa) | ((unsigned)f2bf(fb) << 16);
    float2 wh = *(const float2*)&Wh[hlane * 2];
    float s = fa * wh.x + fb * wh.y;
#pragma unroll
    for (int o = 16; o > 0; o >>= 1) s += __shfl_xor(s, o, 64);
    if (hlane == 0) {
        float lg = s + bh[0];
        lg = fminf(10.0f, fmaxf(-10.0f, lg));
        hl[(size_t)node * NITER + t] = lg;
    }
}

// ---------------- fp32 fallback propagation ----------------
__global__ __launch_bounds__(256) void k_prop(const float* __restrict__ pin,
        float* __restrict__ pout, const int* __restrict__ offs,
        const int2* __restrict__ csr, const float* __restrict__ dinv,
        const float* __restrict__ Wh, const float* __restrict__ bh,
        float* __restrict__ hl, int t) {
    int wid = (blockIdx.x * blockDim.x + threadIdx.x) >> 6;
    int lane = threadIdx.x & 63;
    if (wid >= N_NODES) return;
    float di = dinv[wid];
    float a[4];
    a[0] = di * di * pin[(size_t)wid * 64 + lane];
    a[1] = a[2] = a[3] = 0.f;
    int e0 = offs[wid], e1 = offs[wid + 1];
    for (int eb = e0; eb < e1; eb += 64) {
        int n = e1 - eb; if (n > 64) n = 64;
        int idx = eb + lane;
        int2 ew = csr[idx < e1 ? idx : e1 - 1];
        int j = 0;
        for (; j + 8 <= n; j += 8) {
            float v[8], w[8];
#pragma unroll
            for (int q = 0; q < 8; ++q) {
                int s = __shfl(ew.x, j + q, 64);
                w[q] = __int_as_float(__shfl(ew.y, j + q, 64));
                v[q] = pin[(size_t)s * 64 + lane];
            }
#pragma unroll
            for (int q = 0; q < 8; ++q) a[q & 3] = fmaf(w[q], v[q], a[q & 3]);
        }
        for (; j < n; ++j) {
            int s = __shfl(ew.x, j, 64);
            float w = __int_as_float(__shfl(ew.y, j, 64));
            a[0] = fmaf(w, pin[(size_t)s * 64 + lane], a[0]);
        }
    }
    float acc = (a[0] + a[1]) + (a[2] + a[3]);
    pout[(size_t)wid * 64 + lane] = acc;
    float s = acc * Wh[lane];
#pragma unroll
    for (int o = 32; o > 0; o >>= 1) s += __shfl_xor(s, o, 64);
    if (lane == 0) {
        float lg = s + bh[0];
        lg = fminf(10.0f, fmaxf(-10.0f, lg));
        hl[(size_t)wid * NITER + t] = lg;
    }
}

__global__ void k_p(const float* __restrict__ hl, float* __restrict__ p) {
    int i = blockIdx.x * 256 + threadIdx.x;
    if (i >= N_NODES) return;
    float remain = 1.0f;
    float pv[NITER];
#pragma unroll
    for (int t = 0; t < NITER; ++t) {
        float lg = hl[(size_t)i * NITER + t];
        float lam = 1.0f / (1.0f + expf(-lg));
        pv[t] = lam * remain;
        remain *= (1.0f - lam);
    }
    pv[NITER - 1] += remain;
#pragma unroll
    for (int t = 0; t < NITER; ++t) p[(size_t)i * NITER + t] = pv[t];
}

extern "C" void kernel_launch(void* const* d_in, const int* in_sizes, int n_in,
                              void* d_out, int out_size, void* d_ws, size_t ws_size,
                              hipStream_t stream) {
    const float* x  = (const float*)d_in[0];
    const void*  ei = d_in[1];
    const float* W0 = (const float*)d_in[3];
    const float* b0 = (const float*)d_in[4];
    const float* W1 = (const float*)d_in[5];
    const float* b1 = (const float*)d_in[6];
    const float* Wh = (const float*)d_in[7];
    const float* bh = (const float*)d_in[8];
    float* out = (float*)d_out;

    int* ws_i   = (int*)d_ws;
    int* cnt    = ws_i;
    int* offs   = ws_i + N_NODES;
    int* cursor = ws_i + 2 * N_NODES + 2;       // also hosts bhist/binoffs/bincur
    int* bhist   = cursor;                      // NSUB
    int* binoffs = cursor + 8192;               // NSUB+1
    int* bincur  = cursor + 16384;              // NSUB
    int* part   = ws_i + 3 * N_NODES + 2;
    int* flag   = ws_i + 3 * N_NODES + 66;
    float* dinv = (float*)(ws_i + 3 * N_NODES + 128);
    int2* csr   = (int2*)((char*)d_ws + WS_CSR_OFF);
    _Float16* W0f = (_Float16*)((char*)d_ws + WS_W0F_OFF);
    _Float16* W1f = (_Float16*)((char*)d_ws + WS_W1F_OFF);
    unsigned short* sh0 = (unsigned short*)((char*)d_ws + WS_SH0_OFF);
    unsigned short* sh1 = (unsigned short*)((char*)d_ws + WS_SH1_OFF);
    int2* bin = (int2*)((char*)d_ws + WS_BIN_OFF);

    const int use_w   = ws_size >= WS_NEED_W;
    const int use_bf  = ws_size >= WS_NEED_BF;
    const int use_bin = ws_size >= WS_NEED_BIN;

    hipMemsetAsync(d_ws, 0, (size_t)(3 * N_NODES + 128) * 4, stream);
    k_detect<<<1, 64, 0, stream>>>((const int*)ei, flag);
    k_count_hist<<<1024, 256, 0, stream>>>(ei, flag, cnt, bhist);
    k_scan1<<<SCAN_NB, 256, 0, stream>>>(cnt, part);
    k_scan2<<<1, 256, 0, stream>>>(part, offs);
    k_scan3<<<SCAN_NB, 256, 0, stream>>>(cnt, part, offs);
    k_dinv<<<(N_NODES + 255) / 256, 256, 0, stream>>>(cnt, dinv);
    if (use_bin) {
        k_scan6k<<<1, 256, 0, stream>>>(bhist, binoffs);
        k_bin<<<A1_GRID, 256, 0, stream>>>(ei, flag, binoffs, bincur, bin);
        k_fill_b<<<NBKT, 256, 0, stream>>>(bin, binoffs, offs, dinv, csr);
    } else {
        k_fill_part<<<FILL_GRID, 256, 0, stream>>>(ei, flag, dinv, offs, bincur + 8192, csr);
    }

    if (use_w) {
        k_prep_w<<<72, 256, 0, stream>>>(W0, W1, W0f, W1f);
        k_encoder_mfma<<<(N_NODES + EBM - 1) / EBM, 256, 0, stream>>>(
            x, W0f, b0, W1f, b1, out, sh0, use_bf);
    } else {
        k_encoder<<<N_NODES / 32, 256, 0, stream>>>(x, W0, b0, W1, b1, out);
    }

    float* hl = out + OUT_HL_OFF;
    if (use_bf) {
        for (int it = 0; it < NITER; ++it) {
            const unsigned short* pin_bf = (it & 1) ? sh1 : sh0;
            unsigned short* pout_bf      = (it & 1) ? sh0 : sh1;
            float* pout = out + (size_t)(it + 1) * N_NODES * N_CLASSES;
            k_prop_bf<<<((size_t)N_NODES * 32 + 255) / 256, 256, 0, stream>>>(
                pin_bf, pout, pout_bf, offs, csr, dinv, Wh, bh, hl, it);
        }
    } else {
        for (int it = 0; it < NITER; ++it) {
            const float* pin = out + (size_t)it * N_NODES * N_CLASSES;
            float* pout      = out + (size_t)(it + 1) * N_NODES * N_CLASSES;
            k_prop<<<((size_t)N_NODES * 64 + 255) / 256, 256, 0, stream>>>(
                pin, pout, offs, csr, dinv, Wh, bh, hl, it);
        }
    }
    k_p<<<(N_NODES + 255) / 256, 256, 0, stream>>>(hl, out + OUT_P_OFF);
}

// Round 8
// 992.174 us; speedup vs baseline: 1.1228x; 1.1228x over previous
//
#include <hip/hip_runtime.h>
#include <hip/hip_bf16.h>

#define N_NODES  100000
#define N_EDGES  3200000
#define IN_FEATS 512
#define HIDDEN   256
#define N_CLASSES 64
#define NITER    10

#define SCAN_NB  49   // ceil(100000/2048)

// d_out layout (floats): outputs[11][N][64] | p[N][10] | hl[N][10]
#define OUT_P_OFF  ((size_t)(NITER + 1) * N_NODES * N_CLASSES)
#define OUT_HL_OFF (OUT_P_OFF + (size_t)N_NODES * NITER)

// ws byte offsets (csr region reserves 2*E ints; only E used now)
#define WS_META_INTS (4 * N_NODES + 128)
#define WS_CSR_OFF   ((size_t)WS_META_INTS * 4)
#define WS_W0F_OFF   (WS_CSR_OFF + (size_t)2 * N_EDGES * 4)
#define WS_W1F_OFF   (WS_W0F_OFF + 262144)
#define WS_SH0_OFF   (WS_W1F_OFF + 32768)
#define WS_SH1_OFF   (WS_SH0_OFF + (size_t)N_NODES * 64 * 2)
#define WS_NEED_W    (WS_SH0_OFF)
#define WS_NEED_BF   (WS_SH1_OFF + (size_t)N_NODES * 64 * 2)

typedef _Float16 f16x8 __attribute__((ext_vector_type(8)));
typedef _Float16 f16x4 __attribute__((ext_vector_type(4)));
typedef float    f32x4 __attribute__((ext_vector_type(4)));

__device__ __forceinline__ float bflo(unsigned v) { return __uint_as_float(v << 16); }
__device__ __forceinline__ float bfhi(unsigned v) { return __uint_as_float(v & 0xffff0000u); }
__device__ __forceinline__ unsigned short f2bf(float f) {
    unsigned u = __float_as_uint(f);
    return (unsigned short)((u + 0x7fffu + ((u >> 16) & 1u)) >> 16);
}

// ---------------- dtype detection (int32 vs int64 edge_index) ----------------
__global__ void k_detect(const int* ei, int* flag) {
    if (threadIdx.x == 0 && blockIdx.x == 0) {
        int is64 = 1;
        for (int k = 0; k < 128; ++k) {
            if (ei[2 * k + 1] != 0) { is64 = 0; break; }
        }
        *flag = is64;
    }
}

__device__ __forceinline__ int edge_row(const void* ei, int is64, int e) {
    return is64 ? (int)((const long long*)ei)[e] : ((const int*)ei)[e];
}
__device__ __forceinline__ int edge_col(const void* ei, int is64, int e) {
    return is64 ? (int)((const long long*)ei)[(size_t)N_EDGES + e]
                : ((const int*)ei)[(size_t)N_EDGES + e];
}

__global__ void k_count(const void* ei, const int* flag, int* cnt) {
    int e = blockIdx.x * 256 + threadIdx.x;
    if (e >= N_EDGES) return;
    int is64 = *flag;
    atomicAdd(&cnt[edge_col(ei, is64, e)], 1);
}

__global__ __launch_bounds__(256) void k_scan1(const int* cnt, int* part) {
    __shared__ int sd[256];
    int b = blockIdx.x, t = threadIdx.x;
    int s = 0;
    for (int j = t; j < 2048; j += 256) {
        int idx = b * 2048 + j;
        if (idx < N_NODES) s += cnt[idx];
    }
    sd[t] = s;
    __syncthreads();
    for (int o = 128; o > 0; o >>= 1) {
        if (t < o) sd[t] += sd[t + o];
        __syncthreads();
    }
    if (t == 0) part[b] = sd[0];
}

__global__ __launch_bounds__(256) void k_scan2(int* part, int* offs) {
    __shared__ int sd[256];
    int t = threadIdx.x;
    sd[t] = (t < SCAN_NB) ? part[t] : 0;
    __syncthreads();
    for (int o = 1; o < 256; o <<= 1) {
        int add = (t >= o) ? sd[t - o] : 0;
        __syncthreads();
        sd[t] += add;
        __syncthreads();
    }
    if (t < SCAN_NB) part[t] = (t == 0) ? 0 : sd[t - 1];
    if (t == 0) offs[N_NODES] = N_EDGES;
}

__global__ __launch_bounds__(256) void k_scan3(const int* cnt, const int* part, int* offs) {
    __shared__ int sd[256];
    int b = blockIdx.x, t = threadIdx.x;
    int base = b * 2048 + t * 8;
    int local[8];
    int s = 0;
#pragma unroll
    for (int j = 0; j < 8; ++j) {
        int idx = base + j;
        int v = (idx < N_NODES) ? cnt[idx] : 0;
        local[j] = s;
        s += v;
    }
    sd[t] = s;
    __syncthreads();
    for (int o = 1; o < 256; o <<= 1) {
        int add = (t >= o) ? sd[t - o] : 0;
        __syncthreads();
        sd[t] += add;
        __syncthreads();
    }
    int tbase = part[b] + ((t == 0) ? 0 : sd[t - 1]);
#pragma unroll
    for (int j = 0; j < 8; ++j) {
        int idx = base + j;
        if (idx < N_NODES) offs[idx] = tbase + local[j];
    }
}

__global__ void k_dinv(const int* cnt, float* dinv) {
    int i = blockIdx.x * 256 + threadIdx.x;
    if (i >= N_NODES) return;
    dinv[i] = rsqrtf((float)(cnt[i] + 1));
}

// ---------------- CSR fill: src byte-offset only (4 B/edge) ------------------
__global__ void k_fill(const void* ei, const int* flag,
                       const int* offs, int* cursor, int* csr) {
    int e = blockIdx.x * 256 + threadIdx.x;
    if (e >= N_EDGES) return;
    int is64 = *flag;
    int r = edge_row(ei, is64, e);
    int c = edge_col(ei, is64, e);
    int pos = offs[c] + atomicAdd(&cursor[c], 1);
    csr[pos] = r << 7;   // byte offset into 128B-row bf16 shadow
}

// -------- weight reshuffle to frag-ready fp16 (one dwordx4 per lane-frag) ----
__global__ void k_prep_w(const float* __restrict__ W0, const float* __restrict__ W1,
                         _Float16* __restrict__ W0f, _Float16* __restrict__ W1f) {
    int id = blockIdx.x * 256 + threadIdx.x;
    if (id < 16384) {
        int l = id & 63, c = (id >> 6) & 15, kkg = id >> 10;
        int n = c * 16 + (l & 15);
        int kb = kkg * 32 + ((l >> 4) * 8);
        f16x8 v;
#pragma unroll
        for (int j = 0; j < 8; ++j) v[j] = (_Float16)W0[(size_t)(kb + j) * HIDDEN + n];
        *(f16x8*)&W0f[(size_t)id * 8] = v;
    } else if (id < 16384 + 2048) {
        int id2 = id - 16384;
        int l = id2 & 63, c = (id2 >> 6) & 3, kkg = id2 >> 8;
        int n = c * 16 + (l & 15);
        int kb = kkg * 32 + ((l >> 4) * 8);
        f16x8 v;
#pragma unroll
        for (int j = 0; j < 8; ++j) v[j] = (_Float16)W1[(size_t)(kb + j) * N_CLASSES + n];
        *(f16x8*)&W1f[(size_t)id2 * 8] = v;
    }
}

// ---------------- MFMA fp16 fused encoder (W via LDS dbuf) -------------------
#define EBM 64
#define XS_STRIDE 72
#define H1_STRIDE 264
#define XS0   0
#define XS1   9216
#define WST0  18432
#define WST1  34816
#define W2ST0 34816
#define W2ST1 38912
__global__ __launch_bounds__(256) void k_encoder_mfma(
        const float* __restrict__ x, const _Float16* __restrict__ W0f,
        const float* __restrict__ b0, const _Float16* __restrict__ W1f,
        const float* __restrict__ b1, float* __restrict__ out,
        const float* __restrict__ dinv,
        unsigned short* __restrict__ shadow, int write_shadow) {
    __shared__ char smem[51200];
    const int t = threadIdx.x;
    const int w = t >> 6, l = t & 63;
    const int g = l >> 4, r15 = l & 15;
    const int row0 = blockIdx.x * EBM;
    const int c4 = t & 15;
    const int srow0 = t >> 4;

    f32x4 acc[16];
#pragma unroll
    for (int c = 0; c < 16; ++c) acc[c] = (f32x4){0.f, 0.f, 0.f, 0.f};

    float4 xld[4];
    f16x8 wld[4];
#pragma unroll
    for (int q = 0; q < 4; ++q) {
        int grow = row0 + q * 16 + srow0;
        if (grow >= N_NODES) grow = N_NODES - 1;
        xld[q] = *(const float4*)&x[(size_t)grow * IN_FEATS + c4 * 4];
    }
#pragma unroll
    for (int q = 0; q < 4; ++q) wld[q] = *(const f16x8*)&W0f[(size_t)(q * 256 + t) * 8];
#pragma unroll
    for (int q = 0; q < 4; ++q) {
        f16x4 hv = {(_Float16)xld[q].x, (_Float16)xld[q].y, (_Float16)xld[q].z, (_Float16)xld[q].w};
        *(f16x4*)(smem + XS0 + ((q * 16 + srow0) * XS_STRIDE + c4 * 4) * 2) = hv;
    }
#pragma unroll
    for (int q = 0; q < 4; ++q)
        *(f16x8*)(smem + WST0 + (q * 256 + t) * 16) = wld[q];
    __syncthreads();

    for (int kkg = 0; kkg < 16; ++kkg) {
        const int kc = kkg >> 1, kk = kkg & 1;
        if (kkg < 15) {
#pragma unroll
            for (int q = 0; q < 4; ++q)
                wld[q] = *(const f16x8*)&W0f[(size_t)((kkg + 1) * 1024 + q * 256 + t) * 8];
        }
        if (kk == 0 && kc < 7) {
#pragma unroll
            for (int q = 0; q < 4; ++q) {
                int grow = row0 + q * 16 + srow0;
                if (grow >= N_NODES) grow = N_NODES - 1;
                xld[q] = *(const float4*)&x[(size_t)grow * IN_FEATS + (kc + 1) * 64 + c4 * 4];
            }
        }
        const char* xbase = smem + ((kc & 1) ? XS1 : XS0);
        const char* wbase = smem + ((kkg & 1) ? WST1 : WST0);
        f16x8 af = *(const f16x8*)(xbase + ((w * 16 + r15) * XS_STRIDE + kk * 32 + g * 8) * 2);
#pragma unroll
        for (int c = 0; c < 16; ++c) {
            f16x8 bf = *(const f16x8*)(wbase + ((c << 6) | l) * 16);
            acc[c] = __builtin_amdgcn_mfma_f32_16x16x32_f16(af, bf, acc[c], 0, 0, 0);
        }
        if (kkg < 15) {
            char* wdst = smem + ((kkg & 1) ? WST0 : WST1);
#pragma unroll
            for (int q = 0; q < 4; ++q)
                *(f16x8*)(wdst + (q * 256 + t) * 16) = wld[q];
        }
        if (kk == 1 && kc < 7) {
            char* xdst = smem + ((kc & 1) ? XS0 : XS1);
#pragma unroll
            for (int q = 0; q < 4; ++q) {
                f16x4 hv = {(_Float16)xld[q].x, (_Float16)xld[q].y, (_Float16)xld[q].z, (_Float16)xld[q].w};
                *(f16x4*)(xdst + ((q * 16 + srow0) * XS_STRIDE + c4 * 4) * 2) = hv;
            }
        }
        __syncthreads();
    }

    f16x8 w2ld = *(const f16x8*)&W1f[(size_t)t * 8];
#pragma unroll
    for (int c = 0; c < 16; ++c) {
        float bb = b0[c * 16 + r15];
#pragma unroll
        for (int i = 0; i < 4; ++i) {
            int row = w * 16 + g * 4 + i;
            *(_Float16*)(smem + (row * H1_STRIDE + c * 16 + r15) * 2) =
                (_Float16)fmaxf(acc[c][i] + bb, 0.f);
        }
    }
    *(f16x8*)(smem + W2ST0 + t * 16) = w2ld;
    __syncthreads();

    f32x4 acc2[4];
#pragma unroll
    for (int c = 0; c < 4; ++c) acc2[c] = (f32x4){0.f, 0.f, 0.f, 0.f};
    for (int kkg = 0; kkg < 8; ++kkg) {
        if (kkg < 7) w2ld = *(const f16x8*)&W1f[(size_t)((kkg + 1) * 256 + t) * 8];
        const char* wbase = smem + ((kkg & 1) ? W2ST1 : W2ST0);
        f16x8 af = *(const f16x8*)(smem + ((w * 16 + r15) * H1_STRIDE + kkg * 32 + g * 8) * 2);
#pragma unroll
        for (int c = 0; c < 4; ++c) {
            f16x8 bf = *(const f16x8*)(wbase + ((c << 6) | l) * 16);
            acc2[c] = __builtin_amdgcn_mfma_f32_16x16x32_f16(af, bf, acc2[c], 0, 0, 0);
        }
        if (kkg < 7)
            *(f16x8*)(smem + ((kkg & 1) ? W2ST0 : W2ST1) + t * 16) = w2ld;
        __syncthreads();
    }
#pragma unroll
    for (int c = 0; c < 4; ++c) {
        float bb = b1[c * 16 + r15];
#pragma unroll
        for (int i = 0; i < 4; ++i) {
            int row = row0 + w * 16 + g * 4 + i;
            if (row < N_NODES) {
                float v = acc2[c][i] + bb;
                int col = c * 16 + r15;
                out[(size_t)row * 64 + col] = v;
                if (write_shadow)
                    shadow[(size_t)row * 64 + col] = f2bf(dinv[row] * v);  // pre-scaled s = dinv*h
            }
        }
    }
}

// ---------------- scalar fallback encoder ----------------
__global__ __launch_bounds__(256) void k_encoder(const float* __restrict__ x,
        const float* __restrict__ W0, const float* __restrict__ b0,
        const float* __restrict__ W1, const float* __restrict__ b1,
        float* __restrict__ out) {
    __shared__ float xsh[32][128];
    __shared__ float h1s[32][HIDDEN + 1];
    const int t = threadIdx.x;
    const int rg = t >> 6;
    const int cg = t & 63;
    const size_t row0 = (size_t)blockIdx.x * 32;
    float acc[8][4];
#pragma unroll
    for (int i = 0; i < 8; ++i)
        acc[i][0] = acc[i][1] = acc[i][2] = acc[i][3] = 0.f;
    for (int kc = 0; kc < 4; ++kc) {
        __syncthreads();
#pragma unroll
        for (int q = 0; q < 4; ++q) {
            int idx = t + q * 256;
            int r = idx >> 5, pos = idx & 31;
            *(float4*)&xsh[r][pos * 4] =
                *(const float4*)&x[(row0 + r) * IN_FEATS + kc * 128 + pos * 4];
        }
        __syncthreads();
        for (int kk = 0; kk < 128; kk += 4) {
            float4 xv[8];
#pragma unroll
            for (int i = 0; i < 8; ++i) xv[i] = *(const float4*)&xsh[rg * 8 + i][kk];
#pragma unroll
            for (int j = 0; j < 4; ++j) {
                float4 wv = *(const float4*)&W0[(size_t)(kc * 128 + kk + j) * HIDDEN + cg * 4];
#pragma unroll
                for (int i = 0; i < 8; ++i) {
                    float xj = (&xv[i].x)[j];
                    acc[i][0] = fmaf(xj, wv.x, acc[i][0]);
                    acc[i][1] = fmaf(xj, wv.y, acc[i][1]);
                    acc[i][2] = fmaf(xj, wv.z, acc[i][2]);
                    acc[i][3] = fmaf(xj, wv.w, acc[i][3]);
                }
            }
        }
    }
    float4 bb = *(const float4*)&b0[cg * 4];
#pragma unroll
    for (int i = 0; i < 8; ++i) {
        int r = rg * 8 + i;
        h1s[r][cg * 4 + 0] = fmaxf(acc[i][0] + bb.x, 0.f);
        h1s[r][cg * 4 + 1] = fmaxf(acc[i][1] + bb.y, 0.f);
        h1s[r][cg * 4 + 2] = fmaxf(acc[i][2] + bb.z, 0.f);
        h1s[r][cg * 4 + 3] = fmaxf(acc[i][3] + bb.w, 0.f);
    }
    __syncthreads();
    float a2[8];
#pragma unroll
    for (int i = 0; i < 8; ++i) a2[i] = 0.f;
    for (int k = 0; k < HIDDEN; ++k) {
        float wv = W1[(size_t)k * N_CLASSES + cg];
#pragma unroll
        for (int i = 0; i < 8; ++i) a2[i] = fmaf(h1s[rg * 8 + i][k], wv, a2[i]);
    }
    float bv = b1[cg];
#pragma unroll
    for (int i = 0; i < 8; ++i)
        out[(row0 + rg * 8 + i) * N_CLASSES + cg] = a2[i] + bv;
}

// ------ pre-scaled-shadow propagation: weight-free gather-sum, 2 nodes/wave --
// s[v] = dinv_v * ph_v (bf16).  ph2[c] = dinv_c * (sum_e s[src] + s[c]).
__global__ __launch_bounds__(256) void k_prop_s(
        const unsigned short* __restrict__ pin_s, float* __restrict__ pout,
        unsigned short* __restrict__ pout_s, const int* __restrict__ offs,
        const int* __restrict__ csr, const float* __restrict__ dinv,
        const float* __restrict__ Wh, const float* __restrict__ bh,
        float* __restrict__ hl, int t) {
    int node = (blockIdx.x * 256 + threadIdx.x) >> 5;
    if (node >= N_NODES) return;
    int hlane = threadIdx.x & 31;
    int base = threadIdx.x & 32;   // shfl base of this half-wave
    const char* gbase = (const char*)pin_s + hlane * 4;
    unsigned own = *(const unsigned*)(gbase + ((size_t)node << 7));
    float a0 = bflo(own), a1 = bfhi(own);   // self loop term s[c]
    float c0 = 0.f, c1 = 0.f;
    int e0 = offs[node], e1 = offs[node + 1];
    for (int eb = e0; eb < e1; eb += 32) {
        int n = e1 - eb; if (n > 32) n = 32;
        int idx = eb + hlane;
        int ew = csr[idx < e1 ? idx : e1 - 1];   // pre-shifted byte offset
        int j = 0;
        for (; j + 16 <= n; j += 16) {
            unsigned v[16];
#pragma unroll
            for (int q = 0; q < 16; ++q) {
                int s = __shfl(ew, base + j + q, 64);
                v[q] = *(const unsigned*)(gbase + s);
            }
#pragma unroll
            for (int q = 0; q < 16; ++q) {
                if (q & 1) { c0 += bflo(v[q]); c1 += bfhi(v[q]); }
                else       { a0 += bflo(v[q]); a1 += bfhi(v[q]); }
            }
        }
        for (; j + 8 <= n; j += 8) {
            unsigned v[8];
#pragma unroll
            for (int q = 0; q < 8; ++q) {
                int s = __shfl(ew, base + j + q, 64);
                v[q] = *(const unsigned*)(gbase + s);
            }
#pragma unroll
            for (int q = 0; q < 8; ++q) {
                if (q & 1) { c0 += bflo(v[q]); c1 += bfhi(v[q]); }
                else       { a0 += bflo(v[q]); a1 += bfhi(v[q]); }
            }
        }
        for (; j < n; ++j) {
            int s = __shfl(ew, base + j, 64);
            unsigned v = *(const unsigned*)(gbase + s);
            a0 += bflo(v);
            a1 += bfhi(v);
        }
    }
    float di = dinv[node];
    float fa = di * (a0 + c0), fb = di * (a1 + c1);
    *(float2*)&pout[(size_t)node * 64 + hlane * 2] = make_float2(fa, fb);
    *(unsigned*)&pout_s[(size_t)node * 64 + hlane * 2] =
        (unsigned)f2bf(di * fa) | ((unsigned)f2bf(di * fb) << 16);
    float2 wh = *(const float2*)&Wh[hlane * 2];
    float s = fa * wh.x + fb * wh.y;
#pragma unroll
    for (int o = 16; o > 0; o >>= 1) s += __shfl_xor(s, o, 64);
    if (hlane == 0) {
        float lg = s + bh[0];
        lg = fminf(10.0f, fmaxf(-10.0f, lg));
        hl[(size_t)node * NITER + t] = lg;
    }
}

// ---------------- fp32 fallback propagation (int csr) ----------------
__global__ __launch_bounds__(256) void k_prop(const float* __restrict__ pin,
        float* __restrict__ pout, const int* __restrict__ offs,
        const int* __restrict__ csr, const float* __restrict__ dinv,
        const float* __restrict__ Wh, const float* __restrict__ bh,
        float* __restrict__ hl, int t) {
    int wid = (blockIdx.x * blockDim.x + threadIdx.x) >> 6;
    int lane = threadIdx.x & 63;
    if (wid >= N_NODES) return;
    float di = dinv[wid];
    float a[4];
    a[0] = di * di * pin[(size_t)wid * 64 + lane];
    a[1] = a[2] = a[3] = 0.f;
    int e0 = offs[wid], e1 = offs[wid + 1];
    for (int eb = e0; eb < e1; eb += 64) {
        int n = e1 - eb; if (n > 64) n = 64;
        int idx = eb + lane;
        int ew = csr[idx < e1 ? idx : e1 - 1];
        int j = 0;
        for (; j + 8 <= n; j += 8) {
            float v[8], w[8];
#pragma unroll
            for (int q = 0; q < 8; ++q) {
                int r = __shfl(ew, j + q, 64) >> 7;
                w[q] = dinv[r] * di;
                v[q] = pin[(size_t)r * 64 + lane];
            }
#pragma unroll
            for (int q = 0; q < 8; ++q) a[q & 3] = fmaf(w[q], v[q], a[q & 3]);
        }
        for (; j < n; ++j) {
            int r = __shfl(ew, j, 64) >> 7;
            a[0] = fmaf(dinv[r] * di, pin[(size_t)r * 64 + lane], a[0]);
        }
    }
    float acc = (a[0] + a[1]) + (a[2] + a[3]);
    pout[(size_t)wid * 64 + lane] = acc;
    float s = acc * Wh[lane];
#pragma unroll
    for (int o = 32; o > 0; o >>= 1) s += __shfl_xor(s, o, 64);
    if (lane == 0) {
        float lg = s + bh[0];
        lg = fminf(10.0f, fmaxf(-10.0f, lg));
        hl[(size_t)wid * NITER + t] = lg;
    }
}

__global__ void k_p(const float* __restrict__ hl, float* __restrict__ p) {
    int i = blockIdx.x * 256 + threadIdx.x;
    if (i >= N_NODES) return;
    float remain = 1.0f;
    float pv[NITER];
#pragma unroll
    for (int t = 0; t < NITER; ++t) {
        float lg = hl[(size_t)i * NITER + t];
        float lam = 1.0f / (1.0f + expf(-lg));
        pv[t] = lam * remain;
        remain *= (1.0f - lam);
    }
    pv[NITER - 1] += remain;
#pragma unroll
    for (int t = 0; t < NITER; ++t) p[(size_t)i * NITER + t] = pv[t];
}

extern "C" void kernel_launch(void* const* d_in, const int* in_sizes, int n_in,
                              void* d_out, int out_size, void* d_ws, size_t ws_size,
                              hipStream_t stream) {
    const float* x  = (const float*)d_in[0];
    const void*  ei = d_in[1];
    const float* W0 = (const float*)d_in[3];
    const float* b0 = (const float*)d_in[4];
    const float* W1 = (const float*)d_in[5];
    const float* b1 = (const float*)d_in[6];
    const float* Wh = (const float*)d_in[7];
    const float* bh = (const float*)d_in[8];
    float* out = (float*)d_out;

    int* ws_i   = (int*)d_ws;
    int* cnt    = ws_i;
    int* offs   = ws_i + N_NODES;
    int* cursor = ws_i + 2 * N_NODES + 2;
    int* part   = ws_i + 3 * N_NODES + 2;
    int* flag   = ws_i + 3 * N_NODES + 66;
    float* dinv = (float*)(ws_i + 3 * N_NODES + 128);
    int* csr    = (int*)((char*)d_ws + WS_CSR_OFF);
    _Float16* W0f = (_Float16*)((char*)d_ws + WS_W0F_OFF);
    _Float16* W1f = (_Float16*)((char*)d_ws + WS_W1F_OFF);
    unsigned short* sh0 = (unsigned short*)((char*)d_ws + WS_SH0_OFF);
    unsigned short* sh1 = (unsigned short*)((char*)d_ws + WS_SH1_OFF);

    const int use_w  = ws_size >= WS_NEED_W;
    const int use_bf = ws_size >= WS_NEED_BF;

    hipMemsetAsync(d_ws, 0, (size_t)(3 * N_NODES + 128) * 4, stream);
    k_detect<<<1, 64, 0, stream>>>((const int*)ei, flag);
    k_count<<<(N_EDGES + 255) / 256, 256, 0, stream>>>(ei, flag, cnt);
    k_scan1<<<SCAN_NB, 256, 0, stream>>>(cnt, part);
    k_scan2<<<1, 256, 0, stream>>>(part, offs);
    k_scan3<<<SCAN_NB, 256, 0, stream>>>(cnt, part, offs);
    k_dinv<<<(N_NODES + 255) / 256, 256, 0, stream>>>(cnt, dinv);
    k_fill<<<(N_EDGES + 255) / 256, 256, 0, stream>>>(ei, flag, offs, cursor, csr);

    if (use_w) {
        k_prep_w<<<72, 256, 0, stream>>>(W0, W1, W0f, W1f);
        k_encoder_mfma<<<(N_NODES + EBM - 1) / EBM, 256, 0, stream>>>(
            x, W0f, b0, W1f, b1, out, dinv, sh0, use_bf);
    } else {
        k_encoder<<<N_NODES / 32, 256, 0, stream>>>(x, W0, b0, W1, b1, out);
    }

    float* hl = out + OUT_HL_OFF;
    if (use_bf) {
        for (int it = 0; it < NITER; ++it) {
            const unsigned short* pin_s = (it & 1) ? sh1 : sh0;
            unsigned short* pout_s      = (it & 1) ? sh0 : sh1;
            float* pout = out + (size_t)(it + 1) * N_NODES * N_CLASSES;
            k_prop_s<<<((size_t)N_NODES * 32 + 255) / 256, 256, 0, stream>>>(
                pin_s, pout, pout_s, offs, csr, dinv, Wh, bh, hl, it);
        }
    } else {
        for (int it = 0; it < NITER; ++it) {
            const float* pin = out + (size_t)it * N_NODES * N_CLASSES;
            float* pout      = out + (size_t)(it + 1) * N_NODES * N_CLASSES;
            k_prop<<<((size_t)N_NODES * 64 + 255) / 256, 256, 0, stream>>>(
                pin, pout, offs, csr, dinv, Wh, bh, hl, it);
        }
    }
    k_p<<<(N_NODES + 255) / 256, 256, 0, stream>>>(hl, out + OUT_P_OFF);
}